// Round 12
// baseline (1722.841 us; speedup 1.0000x reference)
//
#include <hip/hip_runtime.h>
#include <hip/hip_bf16.h>

#define T_TOK 16384
#define DDIM  1024
#define NEXP  8
#define HDIM  4096
#define HQ    1024            // H quarter
#define NQ    4
#define TOTR  (2 * T_TOK)

#define BM 128                // down/scan panel rows
#define BK 64

typedef __attribute__((ext_vector_type(8))) short bf16x8;
typedef __attribute__((ext_vector_type(4))) float f32x4;

__device__ __forceinline__ unsigned short f2bf(float f) {
  unsigned int x = __builtin_bit_cast(unsigned int, f);
  x += 0x7fffu + ((x >> 16) & 1u);   // RNE
  return (unsigned short)(x >> 16);
}
__device__ __forceinline__ void gload16(void* lds, const void* g) {
  __builtin_amdgcn_global_load_lds(
      (const __attribute__((address_space(1))) unsigned int*)g,
      (__attribute__((address_space(3))) unsigned int*)lds, 16, 0, 0);
}
__device__ __forceinline__ f32x4 mfma16(bf16x8 a, bf16x8 b, f32x4 c) {
  return __builtin_amdgcn_mfma_f32_16x16x32_bf16(a, b, c, 0, 0, 0);
}

#define BARR  __builtin_amdgcn_s_barrier()
#define LGKM0 do { asm volatile("s_waitcnt lgkmcnt(0)" ::: "memory"); \
                   __builtin_amdgcn_sched_barrier(0); } while (0)
#define VMW(n) do { asm volatile("s_waitcnt vmcnt(" #n ")" ::: "memory"); \
                    __builtin_amdgcn_sched_barrier(0); } while (0)
#define PRIO1 __builtin_amdgcn_s_setprio(1)
#define PRIO0 __builtin_amdgcn_s_setprio(0)

// ---------------- workspace layout (bytes) ----------------
#define OFF_GWSUM  ((size_t)0)           // 8 float (memset)
#define OFF_OFF16  ((size_t)64)          // 16 int
#define OFF_NP     ((size_t)128)         // 3 int: npP, npS, npF
#define OFF_BLK    ((size_t)1024)        // 64*16 int
#define OFF_GBASE  ((size_t)8192)        // 64*16 int
#define OFF_PEXPF  ((size_t)12288)       // 256 int (fused 256-row panels)
#define OFF_PM0F   ((size_t)13312)
#define OFF_PENDF  ((size_t)14336)
#define OFF_PEXPP  ((size_t)16384)       // 512 int each (down 128-row panels)
#define OFF_PM0P   ((size_t)18432)
#define OFF_PENDP  ((size_t)20480)
#define OFF_PEXPS  ((size_t)22528)
#define OFF_PM0S   ((size_t)24576)
#define OFF_PENDS  ((size_t)26624)
#define OFF_TOPE   ((size_t)32768)                          // T*2 int
#define OFF_TOPW   (OFF_TOPE   + (size_t)T_TOK*2*4)         // T*2 float
#define OFF_LRANK  (OFF_TOPW   + (size_t)T_TOK*2*4)         // T uint
#define OFF_ROWTOK (OFF_LRANK  + (size_t)T_TOK*4)           // 2T int
#define OFF_ROWG   (OFF_ROWTOK + (size_t)T_TOK*2*4)         // 2T float
#define OFF_XG     ((size_t)1 << 20)                        // 2T x D bf16 (64MiB)
#define OFF_ACTQ   (OFF_XG   + (size_t)TOTR*DDIM*2)         // 2T x HQ bf16 (64MiB)
#define OFF_W1Q    (OFF_ACTQ + (size_t)TOTR*HQ*2)           // E*HQ*D bf16 (16MiB)
#define OFF_W2Q    (OFF_W1Q  + (size_t)NEXP*HQ*DDIM*2)
#define OFF_WPQ    (OFF_W2Q  + (size_t)NEXP*HQ*DDIM*2)      // E*D*HQ bf16 (16MiB)
#define WS_NEEDED  (OFF_WPQ  + (size_t)NEXP*DDIM*HQ*2 + ((size_t)1<<20))

// ---------------- gating ----------------
__global__ __launch_bounds__(256) void k_gate(
    const float* __restrict__ x, const float* __restrict__ noise,
    const float* __restrict__ gate_w, const float* __restrict__ nw,
    float* __restrict__ gwsum, int* __restrict__ tope, float* __restrict__ topw)
{
  __shared__ float gw_s[NEXP * DDIM];
  __shared__ float blk_gw[NEXP];
  const int tid = threadIdx.x;
  if (tid < NEXP) blk_gw[tid] = 0.f;
  {
    float4* dst = (float4*)gw_s;
    const float4* src = (const float4*)gate_w;
    for (int i = tid; i < NEXP * DDIM / 4; i += 256) dst[i] = src[i];
  }
  __syncthreads();

  const int wv = tid >> 6, lane = tid & 63;
  const int t = blockIdx.x * 4 + wv;

  const float4* xr = (const float4*)(x + (size_t)t * DDIM);
  float4 xv[4];
  #pragma unroll
  for (int c = 0; c < 4; ++c) xv[c] = xr[lane + 64 * c];

  float logit[NEXP];
  #pragma unroll
  for (int e = 0; e < NEXP; ++e) {
    float p = 0.f;
    const float4* g4 = (const float4*)(gw_s + e * DDIM);
    #pragma unroll
    for (int c = 0; c < 4; ++c) {
      float4 g = g4[lane + 64 * c];
      p += xv[c].x * g.x + xv[c].y * g.y + xv[c].z * g.z + xv[c].w * g.w;
    }
    #pragma unroll
    for (int off = 32; off >= 1; off >>= 1) p += __shfl_xor(p, off, 64);
    logit[e] = p;
  }

  if (lane == 0) {
    float m = logit[0];
    #pragma unroll
    for (int e = 1; e < NEXP; ++e) m = fmaxf(m, logit[e]);
    float sm[NEXP]; float s = 0.f;
    #pragma unroll
    for (int e = 0; e < NEXP; ++e) { sm[e] = expf(logit[e] - m); s += sm[e]; }
    float inv = 1.f / s;
    #pragma unroll
    for (int e = 0; e < NEXP; ++e) atomicAdd(&blk_gw[e], sm[e] * inv);

    float ln[NEXP];
    #pragma unroll
    for (int e = 0; e < NEXP; ++e) ln[e] = logit[e] + noise[(size_t)t * NEXP + e] * nw[e];
    int i1 = 0; float v1 = ln[0];
    #pragma unroll
    for (int e = 1; e < NEXP; ++e) if (ln[e] > v1) { v1 = ln[e]; i1 = e; }
    int i2 = -1; float v2 = -3.4e38f;
    #pragma unroll
    for (int e = 0; e < NEXP; ++e) if (e != i1 && ln[e] > v2) { v2 = ln[e]; i2 = e; }
    float b = expf(v2 - v1);
    float wsum = 1.f + b;
    tope[2 * t] = i1; tope[2 * t + 1] = i2;
    topw[2 * t] = 1.f / wsum; topw[2 * t + 1] = b / wsum;
  }
  __syncthreads();
  if (tid < NEXP) atomicAdd(&gwsum[tid], blk_gw[tid]);
}

// per-256-token-block histogram over 16 (expert,region) bins
__global__ __launch_bounds__(256) void k_hist(
    const int* __restrict__ tope, unsigned int* __restrict__ lrank,
    int* __restrict__ blkcnt)
{
  __shared__ int cnt16[16];
  const int tid = threadIdx.x;
  const int t = blockIdx.x * 256 + tid;
  if (tid < 16) cnt16[tid] = 0;
  __syncthreads();
  const int e0 = tope[2 * t], e1 = tope[2 * t + 1];
  const int b0 = 2 * e0 + (e0 < e1 ? 0 : 1);
  const int b1 = 2 * e1 + (e1 < e0 ? 0 : 1);
  const int lr0 = atomicAdd(&cnt16[b0], 1);
  const int lr1 = atomicAdd(&cnt16[b1], 1);
  lrank[t] = (unsigned int)lr0 | ((unsigned int)lr1 << 16);
  __syncthreads();
  if (tid < 16) blkcnt[blockIdx.x * 16 + tid] = cnt16[tid];
}

// single block: prefix over 64 hist blocks x 16 bins, panel tables, loss
__global__ __launch_bounds__(512) void k_scan(
    const int* __restrict__ blkcnt, int* __restrict__ gbase,
    int* __restrict__ off16, int* __restrict__ np,
    int* __restrict__ pexpP, int* __restrict__ pm0P, int* __restrict__ pendP,
    int* __restrict__ pexpS, int* __restrict__ pm0S, int* __restrict__ pendS,
    int* __restrict__ pexpF, int* __restrict__ pm0F, int* __restrict__ pendF,
    const float* __restrict__ gwsum, float* __restrict__ out_loss)
{
  __shared__ int ld[64][16];
  __shared__ int sc[64][16];
  __shared__ int tot[16];
  __shared__ int o16[16];
  const int tid = threadIdx.x;
  for (int i = tid; i < 1024; i += 512) ld[i >> 4][i & 15] = blkcnt[i];
  __syncthreads();
  if (tid < 16) {
    int run = 0;
    for (int i = 0; i < 64; ++i) { sc[i][tid] = run; run += ld[i][tid]; }
    tot[tid] = run;
  }
  __syncthreads();
  if (tid == 0) {
    int o = 0;
    for (int b = 0; b < 16; ++b) { o16[b] = o; off16[b] = o; o += tot[b]; }
    int nP = 0, nS = 0, nF = 0;
    for (int b = 0; b < 16; ++b) {
      const int e = b >> 1, s = b & 1;
      const int beg = o16[b], end = beg + tot[b];
      for (int m = beg; m < end; m += BM) {
        const int me = (m + BM < end) ? (m + BM) : end;
        if (!s) { pexpP[nP] = e; pm0P[nP] = m; pendP[nP] = me; ++nP; }
        else    { pexpS[nS] = e; pm0S[nS] = m; pendS[nS] = me; ++nS; }
      }
      for (int m = beg; m < end; m += 256) {
        pexpF[nF] = e; pm0F[nF] = m;
        pendF[nF] = (m + 256 < end) ? (m + 256) : end; ++nF;
      }
    }
    np[0] = nP; np[1] = nS; np[2] = nF;
    float s = 0.f;
    for (int i = 0; i < NEXP; ++i) {
      float d = gwsum[i] / (float)T_TOK - 1.f / (float)NEXP;
      s += d * d;
    }
    out_loss[0] = (s / (float)NEXP) * 0.01f;
  }
  __syncthreads();
  for (int i = tid; i < 1024; i += 512)
    gbase[i] = o16[i & 15] + sc[i >> 4][i & 15];
}

// gather x -> bf16 rows at deterministic destinations; write row metadata
__global__ __launch_bounds__(256) void k_copy(
    const float* __restrict__ x, const int* __restrict__ tope,
    const float* __restrict__ topw, const unsigned int* __restrict__ lrank,
    const int* __restrict__ gbase,
    int* __restrict__ rowtok, float* __restrict__ rowgate,
    unsigned short* __restrict__ Xg)
{
  const int tid = threadIdx.x;
  const int wv = tid >> 6, lane = tid & 63;
  const int t = blockIdx.x * 4 + wv;
  const int e0 = tope[2 * t], e1 = tope[2 * t + 1];
  const int b0 = 2 * e0 + (e0 < e1 ? 0 : 1);
  const int b1 = 2 * e1 + (e1 < e0 ? 0 : 1);
  const unsigned int lr = lrank[t];
  const int hb = t >> 8;
  const int r0 = gbase[hb * 16 + b0] + (int)(lr & 0xffffu);
  const int r1 = gbase[hb * 16 + b1] + (int)(lr >> 16);
  if (lane == 0) {
    rowtok[r0] = t; rowtok[r1] = t;
    rowgate[r0] = topw[2 * t]; rowgate[r1] = topw[2 * t + 1];
  }
  const float4* xr = (const float4*)(x + (size_t)t * DDIM);
  ushort4 o[4];
  #pragma unroll
  for (int c = 0; c < 4; ++c) {
    float4 v = xr[lane + 64 * c];
    o[c].x = f2bf(v.x); o[c].y = f2bf(v.y); o[c].z = f2bf(v.z); o[c].w = f2bf(v.w);
  }
  ushort4* d0 = (ushort4*)(Xg + (size_t)r0 * DDIM);
  ushort4* d1 = (ushort4*)(Xg + (size_t)r1 * DDIM);
  #pragma unroll
  for (int c = 0; c < 4; ++c) d0[lane + 64 * c] = o[c];
  #pragma unroll
  for (int c = 0; c < 4; ++c) d1[lane + 64 * c] = o[c];
}

// cast quarter q of w1,w2 ([E][HQ rows][D]) and wp ([E][D rows][HQ cols]) -> bf16
__global__ __launch_bounds__(256) void k_castall(
    const float* __restrict__ w1, const float* __restrict__ w2,
    const float* __restrict__ wp,
    unsigned short* __restrict__ w1q, unsigned short* __restrict__ w2q,
    unsigned short* __restrict__ wpq, int q)
{
  const int N4 = NEXP * HQ * DDIM / 4;   // 2M float4 per mat-quarter
  for (int i = blockIdx.x * 256 + threadIdx.x; i < 3 * N4; i += gridDim.x * 256) {
    int j = i;
    float4 v; size_t dstIdx; unsigned short* d;
    if (j < N4) {
      const int c4 = j & 255, rr = j >> 8, e = rr >> 10, r = rr & 1023;
      v = ((const float4*)w1)[((size_t)e * HDIM + q * HQ + r) * 256 + c4];
      d = w1q; dstIdx = (size_t)rr * 256 + c4;
    } else if (j < 2 * N4) {
      j -= N4;
      const int c4 = j & 255, rr = j >> 8, e = rr >> 10, r = rr & 1023;
      v = ((const float4*)w2)[((size_t)e * HDIM + q * HQ + r) * 256 + c4];
      d = w2q; dstIdx = (size_t)rr * 256 + c4;
    } else {
      j -= 2 * N4;
      const int c4 = j & 255, rr = j >> 8;      // rr = e*1024 + drow
      v = ((const float4*)wp)[(size_t)rr * 1024 + q * 256 + c4];
      d = wpq; dstIdx = (size_t)rr * 256 + c4;
    }
    ushort4 o;
    o.x = f2bf(v.x); o.y = f2bf(v.y); o.z = f2bf(v.z); o.w = f2bf(v.w);
    ((ushort4*)d)[dstIdx] = o;
  }
}

// =============== 8-phase fused up+gate GEMM — depth-6 pipeline ==============
// BM=256, BN=128, dual B (W1,W2). 512 thr / 8 waves (2M x 4N).
// LDS (128KB dyn), per slot s (32768 elems at s*32768):
//   Ak0 [0,8192) elems, Ak1 [8192,16384), W1k0 [16384,20480),
//   W1k1 [20480,24576), W2k0 [24576,28672), W2k1 [28672,32768).
// Per K-tile: 4 phases = (W1,kk0),(W2,kk0),(W1,kk1),(W2,kk1), 16 MFMA each.
// Each phase stages the unit(s) freed the previous phase for generation t+2
// -> every staged unit has 6-7 phases in flight; uniform vmcnt(10)/phase
// (per-unit audit: binding units have exactly 10 subsequent loads, FIFO).
// ONE barrier per phase (WAR: staged region's last reader >=1 barrier ago).
#define FGXN 144
__global__ __launch_bounds__(512, 2) void k_fused(
    const unsigned short* __restrict__ Xg,
    const unsigned short* __restrict__ w1q, const unsigned short* __restrict__ w2q,
    const float* __restrict__ b1, const float* __restrict__ b2,
    unsigned short* __restrict__ actq, const int* __restrict__ np,
    const int* __restrict__ pexpF, const int* __restrict__ pm0F,
    const int* __restrict__ pendF, int q)
{
  extern __shared__ unsigned short lds[];
  const int flat = blockIdx.y * FGXN + blockIdx.x;     // grid (144,8) = 1152
  const int CPX = (FGXN * 8) / 8;                      // 144
  const int L = (flat & 7) * CPX + (flat >> 3);        // bijective (1152%8==0)
  const int pidx = L >> 3;
  const int yc = L & 7;                                // 8 x 128-col panels
  if (pidx >= np[2]) return;
  const int e = pexpF[pidx], m0 = pm0F[pidx], mend = pendF[pidx];

  const int tid = threadIdx.x;
  const int wid = tid >> 6, lane = tid & 63;
  const int wm = wid >> 2, wn = wid & 3;               // 2M x 4N
  const int wmb = wm * 128, wnb = wn * 32;
  const int fr = lane & 15, fq = lane >> 4;
  const int rsw = ((fq ^ (fr & 3)) << 3);              // read swizzle (elems)

  const unsigned short* Bw1 = w1q + ((size_t)e * HQ + yc * 128) * DDIM;
  const unsigned short* Bw2 = w2q + ((size_t)e * HQ + yc * 128) * DDIM;

  f32x4 acc1[8][2] = {};
  f32x4 acc2[8][2] = {};
  bf16x8 aA[8], wf[2];

  // A k-half unit: 256 rows x 32 elems; 2 gloads/thread, linear dest
  auto stA = [&](int slot, int kk, int kt) {
    #pragma unroll
    for (int l = 0; l < 2; ++l) {
      const int idx = l * 512 + tid;
      const int row = idx >> 2, seg = idx & 3;
      const int koff = kt * 64 + kk * 32 + ((seg ^ (row & 3)) << 3);
      int arow = m0 + row; if (arow >= TOTR) arow = TOTR - 1;
      gload16(&lds[slot * 32768 + kk * 8192 + idx * 8],
              Xg + (size_t)arow * DDIM + koff);
    }
  };
  // W k-half unit: 128 rows x 32 elems; 1 gload/thread
  auto stW = [&](int slot, int mat, int kk, int kt, const unsigned short* B) {
    const int row = tid >> 2, seg = tid & 3;
    const int koff = kt * 64 + kk * 32 + ((seg ^ (row & 3)) << 3);
    gload16(&lds[slot * 32768 + 16384 + mat * 8192 + kk * 4096 + tid * 8],
            B + (size_t)row * DDIM + koff);
  };
  auto rdA8 = [&](int slot, int kk) {
    #pragma unroll
    for (int mf = 0; mf < 8; ++mf) {
      const int row = wmb + mf * 16 + fr;
      aA[mf] = *(const bf16x8*)&lds[slot * 32768 + kk * 8192 + row * 32 + rsw];
    }
  };
  auto rdW = [&](int slot, int mat, int kk) {
    #pragma unroll
    for (int nf = 0; nf < 2; ++nf) {
      const int row = wnb + nf * 16 + fr;
      wf[nf] = *(const bf16x8*)
          &lds[slot * 32768 + 16384 + mat * 8192 + kk * 4096 + row * 32 + rsw];
    }
  };
  auto MF1 = [&]() {
    PRIO1;
    #pragma unroll
    for (int mf = 0; mf < 8; ++mf)
      #pragma unroll
      for (int nf = 0; nf < 2; ++nf)
        acc1[mf][nf] = mfma16(aA[mf], wf[nf], acc1[mf][nf]);
    PRIO0;
  };
  auto MF2 = [&]() {
    PRIO1;
    #pragma unroll
    for (int mf = 0; mf < 8; ++mf)
      #pragma unroll
      for (int nf = 0; nf < 2; ++nf)
        acc2[mf][nf] = mfma16(aA[mf], wf[nf], acc2[mf][nf]);
    PRIO0;
  };

  // ---- prologue: tile0 full; tile1 minus {Ak1, W2k1} (13 loads) ----
  stA(0, 0, 0); stW(0, 0, 0, 0, Bw1); stW(0, 1, 0, 0, Bw2);
  stA(0, 1, 0); stW(0, 0, 1, 0, Bw1); stW(0, 1, 1, 0, Bw2);
  stA(1, 0, 1); stW(1, 0, 0, 1, Bw1); stW(1, 1, 0, 1, Bw2); stW(1, 0, 1, 1, Bw1);
  VMW(10); BARR;

  // ---- main loop: iterations over tile pairs (2i, 2i+1), i=0..6 ----
  for (int i = 0; i < 7; ++i) {
    const int t1 = 2 * i + 1, t2 = 2 * i + 2, t3 = 2 * i + 3;
    // P1: compute (s0, W1, kk0); stage Ak1(s1,t1), W2k1(s1,t1)
    rdA8(0, 0); rdW(0, 0, 0); stA(1, 1, t1); stW(1, 1, 1, t1, Bw2);
    LGKM0; MF1(); VMW(10); BARR;
    // P2: (s0, W2, kk0); stage W1k0(s0,t2)
    rdW(0, 1, 0); stW(0, 0, 0, t2, Bw1);
    LGKM0; MF2(); VMW(10); BARR;
    // P3: (s0, W1, kk1); stage Ak0(s0,t2), W2k0(s0,t2)
    rdA8(0, 1); rdW(0, 0, 1); stA(0, 0, t2); stW(0, 1, 0, t2, Bw2);
    LGKM0; MF1(); VMW(10); BARR;
    // P4: (s0, W2, kk1); stage W1k1(s0,t2)
    rdW(0, 1, 1); stW(0, 0, 1, t2, Bw1);
    LGKM0; MF2(); VMW(10); BARR;
    // P5: (s1, W1, kk0); stage Ak1(s0,t2), W2k1(s0,t2)
    rdA8(1, 0); rdW(1, 0, 0); stA(0, 1, t2); stW(0, 1, 1, t2, Bw2);
    LGKM0; MF1(); VMW(10); BARR;
    // P6: (s1, W2, kk0); stage W1k0(s1,t3)
    rdW(1, 1, 0); stW(1, 0, 0, t3, Bw1);
    LGKM0; MF2(); VMW(10); BARR;
    // P7: (s1, W1, kk1); stage Ak0(s1,t3), W2k0(s1,t3)
    rdA8(1, 1); rdW(1, 0, 1); stA(1, 0, t3); stW(1, 1, 0, t3, Bw2);
    LGKM0; MF1(); VMW(10); BARR;
    // P8: (s1, W2, kk1); stage W1k1(s1,t3)
    rdW(1, 1, 1); stW(1, 0, 1, t3, Bw1);
    LGKM0; MF2(); VMW(10); BARR;
  }

  // ---- peel: tiles 14,15 ----
  rdA8(0, 0); rdW(0, 0, 0); stA(1, 1, 15); stW(1, 1, 1, 15, Bw2);
  LGKM0; MF1(); VMW(0); BARR;
  rdW(0, 1, 0); LGKM0; MF2();
  rdA8(0, 1); rdW(0, 0, 1); LGKM0; MF1();
  rdW(0, 1, 1); LGKM0; MF2();
  rdA8(1, 0); rdW(1, 0, 0); LGKM0; MF1();
  rdW(1, 1, 0); LGKM0; MF2();
  rdA8(1, 1); rdW(1, 0, 1); LGKM0; MF1();
  rdW(1, 1, 1); LGKM0; MF2();

  // ---- epilogue: act = (h+b1) * silu(g+b2) ----
  const int mcnt = mend - m0;
  #pragma unroll
  for (int mf = 0; mf < 8; ++mf) {
    const int rb = wmb + mf * 16 + (fq << 2);
    #pragma unroll
    for (int nf = 0; nf < 2; ++nf) {
      const int cq = yc * 128 + wnb + nf * 16 + fr;
      const float bb1 = b1[(size_t)e * HDIM + q * HQ + cq];
      const float bb2 = b2[(size_t)e * HDIM + q * HQ + cq];
      #pragma unroll
      for (int j = 0; j < 4; ++j) {
        const int lr = rb + j;
        if (lr < mcnt) {
          const float h = acc1[mf][nf][j] + bb1;
          const float g = acc2[mf][nf][j] + bb2;
          const float s = g / (1.f + expf(-g));
          actq[(size_t)(m0 + lr) * HQ + cq] = f2bf(h * s);
        }
      }
    }
  }
}

// ---------------- down GEMM (R11 proven: dual 64-col panels, 2-phase) -------
#define DBN 64
#define DGX 144
#define DGY 8
template<bool STORE>
__global__ __launch_bounds__(256, 2) void k_down(
    const unsigned short* __restrict__ actq, const unsigned short* __restrict__ wpq,
    const float* __restrict__ bp,
    const int* __restrict__ np, int npIdx,
    const int* __restrict__ pexp, const int* __restrict__ pm0, const int* __restrict__ pend,
    const int* __restrict__ rowtok, const float* __restrict__ rowgate,
    float* __restrict__ Y)
{
  const int flat = blockIdx.y * DGX + blockIdx.x;
  const int CPX = (DGX * DGY) / 8;            // 144 (1152 % 8 == 0, bijective)
  const int L = (flat & 7) * CPX + (flat >> 3);
  const int pidx = L >> 3;                    // 0..143 >= max panels 136
  const int yc = L & 7;                       // 8 x 128-col pair-panels = DDIM
  if (pidx >= np[npIdx]) return;
  const int e = pexp[pidx], m0 = pm0[pidx], mend = pend[pidx];

  __shared__ unsigned short As[BM * BK];    // 16 KB
  __shared__ unsigned short Bs1[DBN * BK];  // 8 KB
  __shared__ unsigned short Bs2[DBN * BK];  // 8 KB

  const int tid = threadIdx.x;
  const int wid = tid >> 6, lane = tid & 63;
  const int wr = wid >> 1, wc = wid & 1;    // 2x2 waves: 64 rows x 32 cols each
  const int fr = lane & 15;
  const int fq = lane >> 4;

  const unsigned short* Bbase1 = wpq + ((size_t)e * DDIM + yc * 128) * HQ;
  const unsigned short* Bbase2 = Bbase1 + (size_t)64 * HQ;

  f32x4 acc1[4][2] = {};
  f32x4 acc2[4][2] = {};

  for (int kt = 0; kt < HQ / BK; ++kt) {
    if (kt > 0) __syncthreads();
    const int k0 = kt * BK;
    #pragma unroll
    for (int it = 0; it < 4; ++it) {
      const int idx = it * 256 + tid;
      const int row = idx >> 3, seg = idx & 7;
      const int koff = ((seg ^ (row & 7)) << 3);
      int arow = m0 + row; if (arow >= TOTR) arow = TOTR - 1;
      gload16(&As[idx * 8], actq + (size_t)arow * HQ + k0 + koff);
    }
    #pragma unroll
    for (int it = 0; it < 2; ++it) {
      const int idx = it * 256 + tid;
      const int row = idx >> 3, seg = idx & 7;
      const int koff = ((seg ^ (row & 7)) << 3);
      gload16(&Bs1[idx * 8], Bbase1 + (size_t)row * HQ + k0 + koff);
    }
    #pragma unroll
    for (int it = 0; it < 2; ++it) {
      const int idx = it * 256 + tid;
      const int row = idx >> 3, seg = idx & 7;
      const int koff = ((seg ^ (row & 7)) << 3);
      gload16(&Bs2[idx * 8], Bbase2 + (size_t)row * HQ + k0 + koff);
    }
    __syncthreads();

    #pragma unroll
    for (int kk = 0; kk < 2; ++kk) {
      bf16x8 b1v[2], b2v[2];
      #pragma unroll
      for (int nf = 0; nf < 2; ++nf) {
        const int row = wc * 32 + nf * 16 + fr;
        const int seg = (kk * 4 + fq) ^ (row & 7);
        b1v[nf] = *(const bf16x8*)&Bs1[row * BK + seg * 8];
        b2v[nf] = *(const bf16x8*)&Bs2[row * BK + seg * 8];
      }
      #pragma unroll
      for (int mf = 0; mf < 4; ++mf) {
        const int row = wr * 64 + mf * 16 + fr;
        const int seg = (kk * 4 + fq) ^ (row & 7);
        bf16x8 av = *(const bf16x8*)&As[row * BK + seg * 8];
        #pragma unroll
        for (int nf = 0; nf < 2; ++nf) {
          acc1[mf][nf] = mfma16(av, b1v[nf], acc1[mf][nf]);
          acc2[mf][nf] = mfma16(av, b2v[nf], acc2[mf][nf]);
        }
      }
    }
  }

  const int mcnt = mend - m0;
  #pragma unroll
  for (int mf = 0; mf < 4; ++mf) {
    const int rb = wr * 64 + mf * 16 + (fq << 2);
    #pragma unroll
    for (int nf = 0; nf < 2; ++nf) {
      const int dg1 = yc * 128 + wc * 32 + nf * 16 + fr;
      const int dg2 = dg1 + 64;
      const float bb1 = bp[(size_t)e * DDIM + dg1];
      const float bb2 = bp[(size_t)e * DDIM + dg2];
      #pragma unroll
      for (int j = 0; j < 4; ++j) {
        const int lr = rb + j;
        if (lr < mcnt) {
          const int r = m0 + lr;
          const float gt = rowgate[r];
          float* yrow = &Y[(size_t)rowtok[r] * DDIM];
          const float o1 = gt * (acc1[mf][nf][j] + bb1);
          const float o2 = gt * (acc2[mf][nf][j] + bb2);
          if (STORE) { yrow[dg1] = o1; yrow[dg2] = o2; }
          else       { yrow[dg1] += o1; yrow[dg2] += o2; }
        }
      }
    }
  }
}

extern "C" void kernel_launch(void* const* d_in, const int* in_sizes, int n_in,
                              void* d_out, int out_size, void* d_ws, size_t ws_size,
                              hipStream_t stream) {
  const float* x      = (const float*)d_in[0];
  const float* noise  = (const float*)d_in[1];
  const float* gate_w = (const float*)d_in[2];
  const float* nw     = (const float*)d_in[3];
  const float* w1     = (const float*)d_in[4];
  const float* b1     = (const float*)d_in[5];
  const float* w2     = (const float*)d_in[6];
  const float* b2     = (const float*)d_in[7];
  const float* wp     = (const float*)d_in[8];
  const float* bp     = (const float*)d_in[9];
  float* y = (float*)d_out;

  if (ws_size < WS_NEEDED) return;   // diagnostic: output stays poisoned

  char* ws = (char*)d_ws;
  float* gwsum   = (float*)(ws + OFF_GWSUM);
  int*   off16   = (int*)(ws + OFF_OFF16);
  int*   np      = (int*)(ws + OFF_NP);
  int*   blkcnt  = (int*)(ws + OFF_BLK);
  int*   gbase   = (int*)(ws + OFF_GBASE);
  int*   pexpF   = (int*)(ws + OFF_PEXPF);
  int*   pm0F    = (int*)(ws + OFF_PM0F);
  int*   pendF   = (int*)(ws + OFF_PENDF);
  int*   pexpP   = (int*)(ws + OFF_PEXPP);
  int*   pm0P    = (int*)(ws + OFF_PM0P);
  int*   pendP   = (int*)(ws + OFF_PENDP);
  int*   pexpS   = (int*)(ws + OFF_PEXPS);
  int*   pm0S    = (int*)(ws + OFF_PM0S);
  int*   pendS   = (int*)(ws + OFF_PENDS);
  int*   tope    = (int*)(ws + OFF_TOPE);
  float* topw    = (float*)(ws + OFF_TOPW);
  unsigned int* lrank = (unsigned int*)(ws + OFF_LRANK);
  int*   rowtok  = (int*)(ws + OFF_ROWTOK);
  float* rowgate = (float*)(ws + OFF_ROWG);
  unsigned short* Xg   = (unsigned short*)(ws + OFF_XG);
  unsigned short* actq = (unsigned short*)(ws + OFF_ACTQ);
  unsigned short* w1q  = (unsigned short*)(ws + OFF_W1Q);
  unsigned short* w2q  = (unsigned short*)(ws + OFF_W2Q);
  unsigned short* wpq  = (unsigned short*)(ws + OFF_WPQ);

  hipMemsetAsync(d_ws, 0, 64, stream);   // gwsum only

  k_gate<<<T_TOK / 4, 256, 0, stream>>>(x, noise, gate_w, nw, gwsum, tope, topw);
  k_hist<<<T_TOK / 256, 256, 0, stream>>>(tope, lrank, blkcnt);
  k_scan<<<1, 512, 0, stream>>>(blkcnt, gbase, off16, np,
                                pexpP, pm0P, pendP, pexpS, pm0S, pendS,
                                pexpF, pm0F, pendF,
                                gwsum, y + (size_t)T_TOK * DDIM);
  k_copy<<<T_TOK / 4, 256, 0, stream>>>(x, tope, topw, lrank, gbase,
                                        rowtok, rowgate, Xg);

  const size_t LDSB = 131072;   // 128 KB dynamic LDS (fused only)
  for (int q = 0; q < NQ; ++q) {
    k_castall<<<3072, 256, 0, stream>>>(w1, w2, wp, w1q, w2q, wpq, q);
    k_fused<<<dim3(FGXN, 8), 512, LDSB, stream>>>(
        Xg, w1q, w2q, b1, b2, actq, np, pexpF, pm0F, pendF, q);
    if (q == 0)
      k_down<true><<<dim3(DGX, DGY), 256, 0, stream>>>(
          actq, wpq, bp, np, 0, pexpP, pm0P, pendP, rowtok, rowgate, y);
    else
      k_down<false><<<dim3(DGX, DGY), 256, 0, stream>>>(
          actq, wpq, bp, np, 0, pexpP, pm0P, pendP, rowtok, rowgate, y);
    k_down<false><<<dim3(DGX, DGY), 256, 0, stream>>>(
        actq, wpq, bp, np, 1, pexpS, pm0S, pendS, rowtok, rowgate, y);
  }
}

// Round 13
// 1663.125 us; speedup vs baseline: 1.0359x; 1.0359x over previous
//
#include <hip/hip_runtime.h>
#include <hip/hip_bf16.h>

#define T_TOK 16384
#define DDIM  1024
#define NEXP  8
#define HDIM  4096
#define HQ    1024            // H quarter
#define NQ    4
#define TOTR  (2 * T_TOK)

#define BM 128
#define BK 64

typedef __attribute__((ext_vector_type(8))) short bf16x8;
typedef __attribute__((ext_vector_type(4))) float f32x4;

__device__ __forceinline__ unsigned short f2bf(float f) {
  unsigned int x = __builtin_bit_cast(unsigned int, f);
  x += 0x7fffu + ((x >> 16) & 1u);   // RNE
  return (unsigned short)(x >> 16);
}
__device__ __forceinline__ void gload16(void* lds, const void* g) {
  __builtin_amdgcn_global_load_lds(
      (const __attribute__((address_space(1))) unsigned int*)g,
      (__attribute__((address_space(3))) unsigned int*)lds, 16, 0, 0);
}
__device__ __forceinline__ f32x4 mfma16(bf16x8 a, bf16x8 b, f32x4 c) {
  return __builtin_amdgcn_mfma_f32_16x16x32_bf16(a, b, c, 0, 0, 0);
}

// ---------------- workspace layout (bytes) ----------------
#define OFF_GWSUM  ((size_t)0)           // 8 float (memset)
#define OFF_OFF16  ((size_t)64)          // 16 int
#define OFF_NP     ((size_t)128)         // 2 int: npP, npS
#define OFF_BLK    ((size_t)1024)        // 64*16 int
#define OFF_GBASE  ((size_t)8192)        // 64*16 int
#define OFF_PEXPP  ((size_t)16384)       // 512 int each
#define OFF_PM0P   ((size_t)18432)
#define OFF_PENDP  ((size_t)20480)
#define OFF_PEXPS  ((size_t)22528)
#define OFF_PM0S   ((size_t)24576)
#define OFF_PENDS  ((size_t)26624)
#define OFF_TOPE   ((size_t)32768)                          // T*2 int
#define OFF_TOPW   (OFF_TOPE   + (size_t)T_TOK*2*4)         // T*2 float
#define OFF_LRANK  (OFF_TOPW   + (size_t)T_TOK*2*4)         // T uint
#define OFF_ROWTOK (OFF_LRANK  + (size_t)T_TOK*4)           // 2T int
#define OFF_ROWG   (OFF_ROWTOK + (size_t)T_TOK*2*4)         // 2T float
#define OFF_XG     ((size_t)1 << 20)                        // 2T x D bf16 (64MiB)
#define OFF_ACTQ   (OFF_XG   + (size_t)TOTR*DDIM*2)         // 2T x HQ bf16 (64MiB)
#define OFF_W1Q    (OFF_ACTQ + (size_t)TOTR*HQ*2)           // E*HQ*D bf16 (16MiB)
#define OFF_W2Q    (OFF_W1Q  + (size_t)NEXP*HQ*DDIM*2)
#define OFF_WPQ    (OFF_W2Q  + (size_t)NEXP*HQ*DDIM*2)      // E*D*HQ bf16 (16MiB)
#define WS_NEEDED  (OFF_WPQ  + (size_t)NEXP*DDIM*HQ*2 + ((size_t)1<<20))

// ---------------- gating ----------------
__global__ __launch_bounds__(256) void k_gate(
    const float* __restrict__ x, const float* __restrict__ noise,
    const float* __restrict__ gate_w, const float* __restrict__ nw,
    float* __restrict__ gwsum, int* __restrict__ tope, float* __restrict__ topw)
{
  __shared__ float gw_s[NEXP * DDIM];
  __shared__ float blk_gw[NEXP];
  const int tid = threadIdx.x;
  if (tid < NEXP) blk_gw[tid] = 0.f;
  {
    float4* dst = (float4*)gw_s;
    const float4* src = (const float4*)gate_w;
    for (int i = tid; i < NEXP * DDIM / 4; i += 256) dst[i] = src[i];
  }
  __syncthreads();

  const int wv = tid >> 6, lane = tid & 63;
  const int t = blockIdx.x * 4 + wv;

  const float4* xr = (const float4*)(x + (size_t)t * DDIM);
  float4 xv[4];
  #pragma unroll
  for (int c = 0; c < 4; ++c) xv[c] = xr[lane + 64 * c];

  float logit[NEXP];
  #pragma unroll
  for (int e = 0; e < NEXP; ++e) {
    float p = 0.f;
    const float4* g4 = (const float4*)(gw_s + e * DDIM);
    #pragma unroll
    for (int c = 0; c < 4; ++c) {
      float4 g = g4[lane + 64 * c];
      p += xv[c].x * g.x + xv[c].y * g.y + xv[c].z * g.z + xv[c].w * g.w;
    }
    #pragma unroll
    for (int off = 32; off >= 1; off >>= 1) p += __shfl_xor(p, off, 64);
    logit[e] = p;
  }

  if (lane == 0) {
    float m = logit[0];
    #pragma unroll
    for (int e = 1; e < NEXP; ++e) m = fmaxf(m, logit[e]);
    float sm[NEXP]; float s = 0.f;
    #pragma unroll
    for (int e = 0; e < NEXP; ++e) { sm[e] = expf(logit[e] - m); s += sm[e]; }
    float inv = 1.f / s;
    #pragma unroll
    for (int e = 0; e < NEXP; ++e) atomicAdd(&blk_gw[e], sm[e] * inv);

    float ln[NEXP];
    #pragma unroll
    for (int e = 0; e < NEXP; ++e) ln[e] = logit[e] + noise[(size_t)t * NEXP + e] * nw[e];
    int i1 = 0; float v1 = ln[0];
    #pragma unroll
    for (int e = 1; e < NEXP; ++e) if (ln[e] > v1) { v1 = ln[e]; i1 = e; }
    int i2 = -1; float v2 = -3.4e38f;
    #pragma unroll
    for (int e = 0; e < NEXP; ++e) if (e != i1 && ln[e] > v2) { v2 = ln[e]; i2 = e; }
    float b = expf(v2 - v1);
    float wsum = 1.f + b;
    tope[2 * t] = i1; tope[2 * t + 1] = i2;
    topw[2 * t] = 1.f / wsum; topw[2 * t + 1] = b / wsum;
  }
  __syncthreads();
  if (tid < NEXP) atomicAdd(&gwsum[tid], blk_gw[tid]);
}

// per-256-token-block histogram over 16 (expert,region) bins
__global__ __launch_bounds__(256) void k_hist(
    const int* __restrict__ tope, unsigned int* __restrict__ lrank,
    int* __restrict__ blkcnt)
{
  __shared__ int cnt16[16];
  const int tid = threadIdx.x;
  const int t = blockIdx.x * 256 + tid;
  if (tid < 16) cnt16[tid] = 0;
  __syncthreads();
  const int e0 = tope[2 * t], e1 = tope[2 * t + 1];
  const int b0 = 2 * e0 + (e0 < e1 ? 0 : 1);
  const int b1 = 2 * e1 + (e1 < e0 ? 0 : 1);
  const int lr0 = atomicAdd(&cnt16[b0], 1);
  const int lr1 = atomicAdd(&cnt16[b1], 1);
  lrank[t] = (unsigned int)lr0 | ((unsigned int)lr1 << 16);
  __syncthreads();
  if (tid < 16) blkcnt[blockIdx.x * 16 + tid] = cnt16[tid];
}

// single block: prefix over 64 hist blocks x 16 bins, panel tables (BM=128), loss
__global__ __launch_bounds__(512) void k_scan(
    const int* __restrict__ blkcnt, int* __restrict__ gbase,
    int* __restrict__ off16, int* __restrict__ np,
    int* __restrict__ pexpP, int* __restrict__ pm0P, int* __restrict__ pendP,
    int* __restrict__ pexpS, int* __restrict__ pm0S, int* __restrict__ pendS,
    const float* __restrict__ gwsum, float* __restrict__ out_loss)
{
  __shared__ int ld[64][16];
  __shared__ int sc[64][16];
  __shared__ int tot[16];
  __shared__ int o16[16];
  const int tid = threadIdx.x;
  for (int i = tid; i < 1024; i += 512) ld[i >> 4][i & 15] = blkcnt[i];
  __syncthreads();
  if (tid < 16) {
    int run = 0;
    for (int i = 0; i < 64; ++i) { sc[i][tid] = run; run += ld[i][tid]; }
    tot[tid] = run;
  }
  __syncthreads();
  if (tid == 0) {
    int o = 0;
    for (int b = 0; b < 16; ++b) { o16[b] = o; off16[b] = o; o += tot[b]; }
    int nP = 0, nS = 0;
    for (int b = 0; b < 16; ++b) {
      const int e = b >> 1, s = b & 1;
      const int beg = o16[b], end = beg + tot[b];
      for (int m = beg; m < end; m += BM) {
        const int me = (m + BM < end) ? (m + BM) : end;
        if (!s) { pexpP[nP] = e; pm0P[nP] = m; pendP[nP] = me; ++nP; }
        else    { pexpS[nS] = e; pm0S[nS] = m; pendS[nS] = me; ++nS; }
      }
    }
    np[0] = nP; np[1] = nS;
    float s = 0.f;
    for (int i = 0; i < NEXP; ++i) {
      float d = gwsum[i] / (float)T_TOK - 1.f / (float)NEXP;
      s += d * d;
    }
    out_loss[0] = (s / (float)NEXP) * 0.01f;
  }
  __syncthreads();
  for (int i = tid; i < 1024; i += 512)
    gbase[i] = o16[i & 15] + sc[i >> 4][i & 15];
}

// gather x -> bf16 rows at deterministic destinations; write row metadata
__global__ __launch_bounds__(256) void k_copy(
    const float* __restrict__ x, const int* __restrict__ tope,
    const float* __restrict__ topw, const unsigned int* __restrict__ lrank,
    const int* __restrict__ gbase,
    int* __restrict__ rowtok, float* __restrict__ rowgate,
    unsigned short* __restrict__ Xg)
{
  const int tid = threadIdx.x;
  const int wv = tid >> 6, lane = tid & 63;
  const int t = blockIdx.x * 4 + wv;
  const int e0 = tope[2 * t], e1 = tope[2 * t + 1];
  const int b0 = 2 * e0 + (e0 < e1 ? 0 : 1);
  const int b1 = 2 * e1 + (e1 < e0 ? 0 : 1);
  const unsigned int lr = lrank[t];
  const int hb = t >> 8;
  const int r0 = gbase[hb * 16 + b0] + (int)(lr & 0xffffu);
  const int r1 = gbase[hb * 16 + b1] + (int)(lr >> 16);
  if (lane == 0) {
    rowtok[r0] = t; rowtok[r1] = t;
    rowgate[r0] = topw[2 * t]; rowgate[r1] = topw[2 * t + 1];
  }
  const float4* xr = (const float4*)(x + (size_t)t * DDIM);
  ushort4 o[4];
  #pragma unroll
  for (int c = 0; c < 4; ++c) {
    float4 v = xr[lane + 64 * c];
    o[c].x = f2bf(v.x); o[c].y = f2bf(v.y); o[c].z = f2bf(v.z); o[c].w = f2bf(v.w);
  }
  ushort4* d0 = (ushort4*)(Xg + (size_t)r0 * DDIM);
  ushort4* d1 = (ushort4*)(Xg + (size_t)r1 * DDIM);
  #pragma unroll
  for (int c = 0; c < 4; ++c) d0[lane + 64 * c] = o[c];
  #pragma unroll
  for (int c = 0; c < 4; ++c) d1[lane + 64 * c] = o[c];
}

// cast quarter q of w1,w2 ([E][HQ rows][D]) and wp ([E][D rows][HQ cols]) -> bf16
__global__ __launch_bounds__(256) void k_castall(
    const float* __restrict__ w1, const float* __restrict__ w2,
    const float* __restrict__ wp,
    unsigned short* __restrict__ w1q, unsigned short* __restrict__ w2q,
    unsigned short* __restrict__ wpq, int q)
{
  const int N4 = NEXP * HQ * DDIM / 4;   // 2M float4 per mat-quarter
  for (int i = blockIdx.x * 256 + threadIdx.x; i < 3 * N4; i += gridDim.x * 256) {
    int j = i;
    float4 v; size_t dstIdx; unsigned short* d;
    if (j < N4) {
      const int c4 = j & 255, rr = j >> 8, e = rr >> 10, r = rr & 1023;
      v = ((const float4*)w1)[((size_t)e * HDIM + q * HQ + r) * 256 + c4];
      d = w1q; dstIdx = (size_t)rr * 256 + c4;
    } else if (j < 2 * N4) {
      j -= N4;
      const int c4 = j & 255, rr = j >> 8, e = rr >> 10, r = rr & 1023;
      v = ((const float4*)w2)[((size_t)e * HDIM + q * HQ + r) * 256 + c4];
      d = w2q; dstIdx = (size_t)rr * 256 + c4;
    } else {
      j -= 2 * N4;
      const int c4 = j & 255, rr = j >> 8;      // rr = e*1024 + drow
      v = ((const float4*)wp)[(size_t)rr * 1024 + q * 256 + c4];
      d = wpq; dstIdx = (size_t)rr * 256 + c4;
    }
    ushort4 o;
    o.x = f2bf(v.x); o.y = f2bf(v.y); o.z = f2bf(v.z); o.w = f2bf(v.w);
    ((ushort4*)d)[dstIdx] = o;
  }
}

// ---------------- fused up+gate GEMM (round-4/11 proven config) --------------
// act = (A@W1 + b1) * silu(A@W2 + b2); 2-phase, BM=128, BN=64 dual-mat,
// 256 thr (2x2 waves of 64x32), gload_lds + both-sides XOR swizzle.
#define FBN 64
#define FGX 280
#define FGY 16
__global__ __launch_bounds__(256, 2) void k_fused(
    const unsigned short* __restrict__ Xg,
    const unsigned short* __restrict__ w1q, const unsigned short* __restrict__ w2q,
    const float* __restrict__ b1, const float* __restrict__ b2,
    unsigned short* __restrict__ actq, const int* __restrict__ np,
    const int* __restrict__ pexpP, const int* __restrict__ pm0P, const int* __restrict__ pendP,
    const int* __restrict__ pexpS, const int* __restrict__ pm0S, const int* __restrict__ pendS,
    int q)
{
  const int flat = blockIdx.y * FGX + blockIdx.x;
  const int CPX = (FGX * FGY) / 8;            // 560 (4480 % 8 == 0, bijective)
  const int L = (flat & 7) * CPX + (flat >> 3);
  const int pidx = L >> 4;                    // 0..279 >= max panels 272
  const int yc = L & 15;                      // 16 x 64-col panels = HQ
  const int nP = np[0], nS = np[1];
  int e, m0, mend;
  if (pidx < nP)            { e = pexpP[pidx]; m0 = pm0P[pidx]; mend = pendP[pidx]; }
  else if (pidx < nP + nS)  { int s = pidx - nP; e = pexpS[s]; m0 = pm0S[s]; mend = pendS[s]; }
  else return;

  __shared__ unsigned short As[BM * BK];   // 16 KB
  __shared__ unsigned short B1s[FBN * BK]; // 8 KB
  __shared__ unsigned short B2s[FBN * BK]; // 8 KB

  const int tid = threadIdx.x;
  const int wid = tid >> 6, lane = tid & 63;
  const int wr = wid >> 1, wc = wid & 1;   // 2x2 waves: 64 rows x 32 cols each
  const int fr = lane & 15;
  const int fq = lane >> 4;

  const unsigned short* Bbase1 = w1q + ((size_t)e * HQ + yc * FBN) * DDIM;
  const unsigned short* Bbase2 = w2q + ((size_t)e * HQ + yc * FBN) * DDIM;

  f32x4 acc1[4][2] = {};
  f32x4 acc2[4][2] = {};

  for (int kt = 0; kt < DDIM / BK; ++kt) {
    if (kt > 0) __syncthreads();
    const int k0 = kt * BK;
    #pragma unroll
    for (int it = 0; it < 4; ++it) {
      const int idx = it * 256 + tid;
      const int row = idx >> 3, seg = idx & 7;
      const int koff = ((seg ^ (row & 7)) << 3);
      int arow = m0 + row; if (arow >= TOTR) arow = TOTR - 1;
      gload16(&As[idx * 8], Xg + (size_t)arow * DDIM + k0 + koff);
    }
    #pragma unroll
    for (int it = 0; it < 2; ++it) {
      const int idx = it * 256 + tid;
      const int row = idx >> 3, seg = idx & 7;
      const int koff = ((seg ^ (row & 7)) << 3);
      gload16(&B1s[idx * 8], Bbase1 + (size_t)row * DDIM + k0 + koff);
    }
    #pragma unroll
    for (int it = 0; it < 2; ++it) {
      const int idx = it * 256 + tid;
      const int row = idx >> 3, seg = idx & 7;
      const int koff = ((seg ^ (row & 7)) << 3);
      gload16(&B2s[idx * 8], Bbase2 + (size_t)row * DDIM + k0 + koff);
    }
    __syncthreads();

    #pragma unroll
    for (int kk = 0; kk < 2; ++kk) {
      bf16x8 b1v[2], b2v[2];
      #pragma unroll
      for (int nf = 0; nf < 2; ++nf) {
        const int row = wc * 32 + nf * 16 + fr;
        const int seg = (kk * 4 + fq) ^ (row & 7);
        b1v[nf] = *(const bf16x8*)&B1s[row * BK + seg * 8];
        b2v[nf] = *(const bf16x8*)&B2s[row * BK + seg * 8];
      }
      #pragma unroll
      for (int mf = 0; mf < 4; ++mf) {
        const int row = wr * 64 + mf * 16 + fr;
        const int seg = (kk * 4 + fq) ^ (row & 7);
        bf16x8 av = *(const bf16x8*)&As[row * BK + seg * 8];
        #pragma unroll
        for (int nf = 0; nf < 2; ++nf) {
          acc1[mf][nf] = mfma16(av, b1v[nf], acc1[mf][nf]);
          acc2[mf][nf] = mfma16(av, b2v[nf], acc2[mf][nf]);
        }
      }
    }
  }

  // epilogue: C/D layout col=lane&15, row=(lane>>4)*4+j
  const int mcnt = mend - m0;
  #pragma unroll
  for (int mf = 0; mf < 4; ++mf) {
    const int rb = wr * 64 + mf * 16 + (fq << 2);
    #pragma unroll
    for (int nf = 0; nf < 2; ++nf) {
      const int cq = yc * FBN + wc * 32 + nf * 16 + fr;
      const float bb1 = b1[(size_t)e * HDIM + q * HQ + cq];
      const float bb2 = b2[(size_t)e * HDIM + q * HQ + cq];
      #pragma unroll
      for (int j = 0; j < 4; ++j) {
        const int lr = rb + j;
        if (lr < mcnt) {
          float h = acc1[mf][nf][j] + bb1;
          float g = acc2[mf][nf][j] + bb2;
          float s = g / (1.f + expf(-g));
          actq[(size_t)(m0 + lr) * HQ + cq] = f2bf(h * s);
        }
      }
    }
  }
}

// ---------------- down GEMM (dual 64-col panels sharing A, mirrors k_fused) --
// Y[tok, d] (=|+=) gate * (act@wp^T + bp), K = HQ = 1024. 2-phase, BM=128,
// two 64-col B panels (cols yc*128 .. yc*128+127), 256 thr, acc 64 f32.
#define DBN 64
#define DGX 144
#define DGY 8
template<bool STORE>
__global__ __launch_bounds__(256, 2) void k_down(
    const unsigned short* __restrict__ actq, const unsigned short* __restrict__ wpq,
    const float* __restrict__ bp,
    const int* __restrict__ np, int npIdx,
    const int* __restrict__ pexp, const int* __restrict__ pm0, const int* __restrict__ pend,
    const int* __restrict__ rowtok, const float* __restrict__ rowgate,
    float* __restrict__ Y)
{
  const int flat = blockIdx.y * DGX + blockIdx.x;
  const int CPX = (DGX * DGY) / 8;            // 144 (1152 % 8 == 0, bijective)
  const int L = (flat & 7) * CPX + (flat >> 3);
  const int pidx = L >> 3;                    // 0..143 >= max panels 136
  const int yc = L & 7;                       // 8 x 128-col pair-panels = DDIM
  if (pidx >= np[npIdx]) return;
  const int e = pexp[pidx], m0 = pm0[pidx], mend = pend[pidx];

  __shared__ unsigned short As[BM * BK];    // 16 KB
  __shared__ unsigned short Bs1[DBN * BK];  // 8 KB
  __shared__ unsigned short Bs2[DBN * BK];  // 8 KB

  const int tid = threadIdx.x;
  const int wid = tid >> 6, lane = tid & 63;
  const int wr = wid >> 1, wc = wid & 1;    // 2x2 waves: 64 rows x 32 cols each
  const int fr = lane & 15;
  const int fq = lane >> 4;

  const unsigned short* Bbase1 = wpq + ((size_t)e * DDIM + yc * 128) * HQ;
  const unsigned short* Bbase2 = Bbase1 + (size_t)64 * HQ;

  f32x4 acc1[4][2] = {};
  f32x4 acc2[4][2] = {};

  for (int kt = 0; kt < HQ / BK; ++kt) {
    if (kt > 0) __syncthreads();
    const int k0 = kt * BK;
    #pragma unroll
    for (int it = 0; it < 4; ++it) {
      const int idx = it * 256 + tid;
      const int row = idx >> 3, seg = idx & 7;
      const int koff = ((seg ^ (row & 7)) << 3);
      int arow = m0 + row; if (arow >= TOTR) arow = TOTR - 1;
      gload16(&As[idx * 8], actq + (size_t)arow * HQ + k0 + koff);
    }
    #pragma unroll
    for (int it = 0; it < 2; ++it) {
      const int idx = it * 256 + tid;
      const int row = idx >> 3, seg = idx & 7;
      const int koff = ((seg ^ (row & 7)) << 3);
      gload16(&Bs1[idx * 8], Bbase1 + (size_t)row * HQ + k0 + koff);
    }
    #pragma unroll
    for (int it = 0; it < 2; ++it) {
      const int idx = it * 256 + tid;
      const int row = idx >> 3, seg = idx & 7;
      const int koff = ((seg ^ (row & 7)) << 3);
      gload16(&Bs2[idx * 8], Bbase2 + (size_t)row * HQ + k0 + koff);
    }
    __syncthreads();

    #pragma unroll
    for (int kk = 0; kk < 2; ++kk) {
      bf16x8 b1v[2], b2v[2];
      #pragma unroll
      for (int nf = 0; nf < 2; ++nf) {
        const int row = wc * 32 + nf * 16 + fr;
        const int seg = (kk * 4 + fq) ^ (row & 7);
        b1v[nf] = *(const bf16x8*)&Bs1[row * BK + seg * 8];
        b2v[nf] = *(const bf16x8*)&Bs2[row * BK + seg * 8];
      }
      #pragma unroll
      for (int mf = 0; mf < 4; ++mf) {
        const int row = wr * 64 + mf * 16 + fr;
        const int seg = (kk * 4 + fq) ^ (row & 7);
        bf16x8 av = *(const bf16x8*)&As[row * BK + seg * 8];
        #pragma unroll
        for (int nf = 0; nf < 2; ++nf) {
          acc1[mf][nf] = mfma16(av, b1v[nf], acc1[mf][nf]);
          acc2[mf][nf] = mfma16(av, b2v[nf], acc2[mf][nf]);
        }
      }
    }
  }

  const int mcnt = mend - m0;
  #pragma unroll
  for (int mf = 0; mf < 4; ++mf) {
    const int rb = wr * 64 + mf * 16 + (fq << 2);
    #pragma unroll
    for (int nf = 0; nf < 2; ++nf) {
      const int dg1 = yc * 128 + wc * 32 + nf * 16 + fr;
      const int dg2 = dg1 + 64;
      const float bb1 = bp[(size_t)e * DDIM + dg1];
      const float bb2 = bp[(size_t)e * DDIM + dg2];
      #pragma unroll
      for (int j = 0; j < 4; ++j) {
        const int lr = rb + j;
        if (lr < mcnt) {
          const int r = m0 + lr;
          const float gt = rowgate[r];
          float* yrow = &Y[(size_t)rowtok[r] * DDIM];
          const float o1 = gt * (acc1[mf][nf][j] + bb1);
          const float o2 = gt * (acc2[mf][nf][j] + bb2);
          if (STORE) { yrow[dg1] = o1; yrow[dg2] = o2; }
          else       { yrow[dg1] += o1; yrow[dg2] += o2; }
        }
      }
    }
  }
}

extern "C" void kernel_launch(void* const* d_in, const int* in_sizes, int n_in,
                              void* d_out, int out_size, void* d_ws, size_t ws_size,
                              hipStream_t stream) {
  const float* x      = (const float*)d_in[0];
  const float* noise  = (const float*)d_in[1];
  const float* gate_w = (const float*)d_in[2];
  const float* nw     = (const float*)d_in[3];
  const float* w1     = (const float*)d_in[4];
  const float* b1     = (const float*)d_in[5];
  const float* w2     = (const float*)d_in[6];
  const float* b2     = (const float*)d_in[7];
  const float* wp     = (const float*)d_in[8];
  const float* bp     = (const float*)d_in[9];
  float* y = (float*)d_out;

  if (ws_size < WS_NEEDED) return;   // diagnostic: output stays poisoned

  char* ws = (char*)d_ws;
  float* gwsum   = (float*)(ws + OFF_GWSUM);
  int*   off16   = (int*)(ws + OFF_OFF16);
  int*   np      = (int*)(ws + OFF_NP);
  int*   blkcnt  = (int*)(ws + OFF_BLK);
  int*   gbase   = (int*)(ws + OFF_GBASE);
  int*   pexpP   = (int*)(ws + OFF_PEXPP);
  int*   pm0P    = (int*)(ws + OFF_PM0P);
  int*   pendP   = (int*)(ws + OFF_PENDP);
  int*   pexpS   = (int*)(ws + OFF_PEXPS);
  int*   pm0S    = (int*)(ws + OFF_PM0S);
  int*   pendS   = (int*)(ws + OFF_PENDS);
  int*   tope    = (int*)(ws + OFF_TOPE);
  float* topw    = (float*)(ws + OFF_TOPW);
  unsigned int* lrank = (unsigned int*)(ws + OFF_LRANK);
  int*   rowtok  = (int*)(ws + OFF_ROWTOK);
  float* rowgate = (float*)(ws + OFF_ROWG);
  unsigned short* Xg   = (unsigned short*)(ws + OFF_XG);
  unsigned short* actq = (unsigned short*)(ws + OFF_ACTQ);
  unsigned short* w1q  = (unsigned short*)(ws + OFF_W1Q);
  unsigned short* w2q  = (unsigned short*)(ws + OFF_W2Q);
  unsigned short* wpq  = (unsigned short*)(ws + OFF_WPQ);

  hipMemsetAsync(d_ws, 0, 64, stream);   // gwsum only

  k_gate<<<T_TOK / 4, 256, 0, stream>>>(x, noise, gate_w, nw, gwsum, tope, topw);
  k_hist<<<T_TOK / 256, 256, 0, stream>>>(tope, lrank, blkcnt);
  k_scan<<<1, 512, 0, stream>>>(blkcnt, gbase, off16, np,
                                pexpP, pm0P, pendP, pexpS, pm0S, pendS,
                                gwsum, y + (size_t)T_TOK * DDIM);
  k_copy<<<T_TOK / 4, 256, 0, stream>>>(x, tope, topw, lrank, gbase,
                                        rowtok, rowgate, Xg);

  for (int q = 0; q < NQ; ++q) {
    k_castall<<<3072, 256, 0, stream>>>(w1, w2, wp, w1q, w2q, wpq, q);
    k_fused<<<dim3(FGX, FGY), 256, 0, stream>>>(
        Xg, w1q, w2q, b1, b2, actq, np,
        pexpP, pm0P, pendP, pexpS, pm0S, pendS, q);
    if (q == 0)
      k_down<true><<<dim3(DGX, DGY), 256, 0, stream>>>(
          actq, wpq, bp, np, 0, pexpP, pm0P, pendP, rowtok, rowgate, y);
    else
      k_down<false><<<dim3(DGX, DGY), 256, 0, stream>>>(
          actq, wpq, bp, np, 0, pexpP, pm0P, pendP, rowtok, rowgate, y);
    k_down<false><<<dim3(DGX, DGY), 256, 0, stream>>>(
        actq, wpq, bp, np, 1, pexpS, pm0S, pendS, rowtok, rowgate, y);
  }
}